// Round 17
// baseline (107.603 us; speedup 1.0000x reference)
//
#include <hip/hip_runtime.h>
#include <math.h>

#define TWO_PI_F 6.283185307179586f
#define WROWS 256          // rows per wave-tile (3 KB LDS per buffer)
#define TPW   4            // tiles per wave (contiguous)

typedef float f32x4 __attribute__((ext_vector_type(4)));

__device__ __forceinline__ int lower_bound_dev(const int* __restrict__ b,
                                               int n, int g) {
    int lo = 0, hi = n;
    while (lo < hi) {
        int mid = (lo + hi) >> 1;
        if (b[mid] < g) lo = mid + 1; else hi = mid;
    }
    return lo;
}

// ONE prep kernel, role-split by global thread id:
//   [0, G)            : rotation matrix R[g] (12 floats, rows at f4 0,1,2)
//   [G, +(G+1))       : nstart[g] = lower_bound(node_batch, g)
//   [.., +(G+1))      : estart[g] = lower_bound(edge_batch, g)
//   [.., +TE+TN)      : tileg[t]: t<TE -> edge_batch[t*WROWS], else node
__global__ void prep_kernel(const float* __restrict__ axis,
                            const float* __restrict__ angle,
                            const float* __restrict__ apply_rand,
                            const int* __restrict__ nb, int N,
                            const int* __restrict__ eb, int E, int G,
                            float* __restrict__ R,
                            int* __restrict__ nstart, int* __restrict__ estart,
                            int* __restrict__ tileg, int TE, int TN) {
    int i = blockIdx.x * blockDim.x + threadIdx.x;
    if (i < G) {
        int g = i;
        float a = axis[3 * g + 0];
        float b = axis[3 * g + 1];
        float c = axis[3 * g + 2];
        float inv = rsqrtf(a * a + b * b + c * c);
        a *= inv; b *= inv; c *= inv;
        float th = angle[g] * TWO_PI_F;
        float s, co;
        sincosf(th, &s, &co);
        float omc = 1.0f - co;

        float r00 = 1.0f - omc * (b * b + c * c);
        float r01 = -s * c + omc * (a * b);
        float r02 =  s * b + omc * (a * c);
        float r10 =  s * c + omc * (a * b);
        float r11 = 1.0f - omc * (a * a + c * c);
        float r12 = -s * a + omc * (b * c);
        float r20 = -s * b + omc * (a * c);
        float r21 =  s * a + omc * (b * c);
        float r22 = 1.0f - omc * (a * a + b * b);

        if (!(apply_rand[g] < 0.5f)) {
            r00 = 1.0f; r01 = 0.0f; r02 = 0.0f;
            r10 = 0.0f; r11 = 1.0f; r12 = 0.0f;
            r20 = 0.0f; r21 = 0.0f; r22 = 1.0f;
        }
        float4* Rg = reinterpret_cast<float4*>(R + 12 * (size_t)g);
        Rg[0] = make_float4(r00, r01, r02, 0.0f);
        Rg[1] = make_float4(r10, r11, r12, 0.0f);
        Rg[2] = make_float4(r20, r21, r22, 0.0f);
        return;
    }
    i -= G;
    if (i < G + 1) { nstart[i] = lower_bound_dev(nb, N, i); return; }
    i -= (G + 1);
    if (i < G + 1) { estart[i] = lower_bound_dev(eb, E, i); return; }
    i -= (G + 1);
    if (i < TE) {
        size_t rb = (size_t)i * WROWS;
        if (rb > (size_t)(E - 1)) rb = (size_t)(E - 1);
        tileg[i] = eb[rb];
        return;
    }
    i -= TE;
    if (i < TN) {
        int rb = i * WROWS;
        if (rb > N - 1) rb = N - 1;
        tileg[TE + i] = nb[rb];
        return;
    }
}

// Fused PIPELINED apply: ONE WAVE per block, TPW contiguous tiles per wave.
// Tile t+1's global loads + start[]-walk are issued BEFORE consuming tile t,
// so (no barriers anywhere, wave-private LDS, counted vmcnt) they stay in
// flight across t's entire LDS/rotate/store phase — raising the wave's
// load-issue duty cycle, which is the limiter now that TLP is capped (~20
// waves/CU regardless of launch shape, R15/R16 measured). Rows clamped to
// n-1 in the walk (R12 lesson). NT stores.
__global__ __launch_bounds__(64) void apply_fused_pipe(
        const float* __restrict__ ev, float* __restrict__ eo, int E, int TE,
        const float* __restrict__ xv, float* __restrict__ xo, int N, int TN,
        const float* __restrict__ yv, float* __restrict__ yo, int G, int TT,
        const int* __restrict__ estart, const int* __restrict__ nstart,
        const int* __restrict__ tileg,
        const float* __restrict__ R) {
    __shared__ float buf[2][WROWS * 3];
    const int lane = threadIdx.x;
    const int base = blockIdx.x * TPW;
    if (base >= TT) return;

    // ---- per-tile issue: resolve segment, fire 3 float4 loads, walk gs ----
    auto issue = [&](int t,
                     float*& o, size_t& rb, int& rows, int& f4h, int& tf,
                     float4& r0, float4& r1, float4& r2, float& rT, int gs[4]) {
        const float* v; const int* start; int n; bool hasB;
        if (t < TE) {
            v = ev; o = eo; start = estart; n = E; hasB = true;
            rb = (size_t)t * WROWS;
        } else if (t < TE + TN) {
            v = xv; o = xo; start = nstart; n = N; hasB = true;
            rb = (size_t)(t - TE) * WROWS;
        } else {
            v = yv; o = yo; start = nullptr; n = G; hasB = false;
            rb = (size_t)(t - TE - TN) * WROWS;
        }
        rows = n - (int)rb;
        if (rows > WROWS) rows = WROWS;
        int fh = rows * 3;
        f4h = fh >> 2;
        tf = fh & 3;
        const float4* src = reinterpret_cast<const float4*>(v + rb * 3);
        r0 = (lane < f4h)       ? src[lane]       : make_float4(0, 0, 0, 0);
        r1 = (lane + 64 < f4h)  ? src[lane + 64]  : make_float4(0, 0, 0, 0);
        r2 = (lane + 128 < f4h) ? src[lane + 128] : make_float4(0, 0, 0, 0);
        rT = (tf && lane < tf) ? v[rb * 3 + (((size_t)f4h) << 2) + lane] : 0.f;
        if (hasB) {
            int g = tileg[t];                  // broadcast scalar load
            const int rowMax = n - 1;
            int row0 = (int)rb + 4 * lane;
#pragma unroll
            for (int r = 0; r < 4; ++r) {
                int row = row0 + r;
                if (row > rowMax) row = rowMax;
                while (start[g + 1] <= row) ++g;   // <=~3 steps per tile
                gs[r] = g;
            }
        } else {
            int b = (int)rb + 4 * lane;
            gs[0] = b; gs[1] = b + 1; gs[2] = b + 2; gs[3] = b + 3;
        }
    };

    // ---- per-tile consume: LDS shuffle, rotate, LDS shuffle, NT store ----
    auto consume = [&](int bsel,
                       float* o, size_t rb, int rows, int f4h, int tf,
                       float4 r0, float4 r1, float4 r2, float rT,
                       const int gs[4]) {
        float* b = buf[bsel];
        float4* b4 = reinterpret_cast<float4*>(b);
        if (lane < f4h)       b4[lane]       = r0;
        if (lane + 64 < f4h)  b4[lane + 64]  = r1;
        if (lane + 128 < f4h) b4[lane + 128] = r2;
        if (tf && lane < tf)  b[(f4h << 2) + lane] = rT;

        int nRow4 = rows >> 2;
        if (lane < nRow4) {
            float4 p0 = b4[3 * lane + 0];
            float4 p1 = b4[3 * lane + 1];
            float4 p2 = b4[3 * lane + 2];
            float rowsv[4][3] = {
                {p0.x, p0.y, p0.z},
                {p0.w, p1.x, p1.y},
                {p1.z, p1.w, p2.x},
                {p2.y, p2.z, p2.w}};
            float oo[12];
#pragma unroll
            for (int r = 0; r < 4; ++r) {
                const float4* Rg = reinterpret_cast<const float4*>(R + 12 * (size_t)gs[r]);
                float4 R0 = Rg[0];
                float4 R1 = Rg[1];
                float4 R2 = Rg[2];
                float v0 = rowsv[r][0], v1 = rowsv[r][1], v2 = rowsv[r][2];
                oo[3 * r + 0] = R0.x * v0 + R0.y * v1 + R0.z * v2;
                oo[3 * r + 1] = R1.x * v0 + R1.y * v1 + R1.z * v2;
                oo[3 * r + 2] = R2.x * v0 + R2.y * v1 + R2.z * v2;
            }
            b4[3 * lane + 0] = make_float4(oo[0], oo[1], oo[2], oo[3]);
            b4[3 * lane + 1] = make_float4(oo[4], oo[5], oo[6], oo[7]);
            b4[3 * lane + 2] = make_float4(oo[8], oo[9], oo[10], oo[11]);
        }
        // (rows % 4 tail: E, N, G all divisible by 4 here.)

        const f32x4* rb4 = reinterpret_cast<const f32x4*>(b);
        f32x4* dst = reinterpret_cast<f32x4*>(o + rb * 3);
        if (lane < f4h) {
            f32x4 val = rb4[lane];
            __builtin_nontemporal_store(val, &dst[lane]);
        }
        if (lane + 64 < f4h) {
            f32x4 val = rb4[lane + 64];
            __builtin_nontemporal_store(val, &dst[lane + 64]);
        }
        if (lane + 128 < f4h) {
            f32x4 val = rb4[lane + 128];
            __builtin_nontemporal_store(val, &dst[lane + 128]);
        }
        if (tf && lane < tf) {
            int fi = (f4h << 2) + lane;
            __builtin_nontemporal_store(b[fi], &o[rb * 3 + fi]);
        }
    };

    // ---- software pipeline over TPW contiguous tiles (fully unrolled) ----
    float* oA; size_t rbA; int rowsA, f4A, tfA, gsA[4];
    float4 A0, A1, A2; float AT;
    float* oB; size_t rbB; int rowsB, f4B, tfB, gsB[4];
    float4 B0, B1, B2; float BT;

    issue(base, oA, rbA, rowsA, f4A, tfA, A0, A1, A2, AT, gsA);
#pragma unroll
    for (int i = 0; i < TPW; ++i) {
        int t = base + i;
        if (t >= TT) break;
        bool hasNext = (i + 1 < TPW) && (t + 1 < TT);
        if (hasNext) {
            if (i & 1) issue(t + 1, oA, rbA, rowsA, f4A, tfA, A0, A1, A2, AT, gsA);
            else       issue(t + 1, oB, rbB, rowsB, f4B, tfB, B0, B1, B2, BT, gsB);
        }
        if (i & 1) consume(i & 1, oB, rbB, rowsB, f4B, tfB, B0, B1, B2, BT, gsB);
        else       consume(i & 1, oA, rbA, rowsA, f4A, tfA, A0, A1, A2, AT, gsA);
    }
}

extern "C" void kernel_launch(void* const* d_in, const int* in_sizes, int n_in,
                              void* d_out, int out_size, void* d_ws, size_t ws_size,
                              hipStream_t stream) {
    const float* x          = (const float*)d_in[0];
    const float* edge_attr  = (const float*)d_in[1];
    const float* y          = (const float*)d_in[2];
    const int*   node_batch = (const int*)d_in[3];
    const int*   edge_batch = (const int*)d_in[4];
    const float* axis       = (const float*)d_in[5];
    const float* angle      = (const float*)d_in[6];
    const float* apply_rand = (const float*)d_in[7];

    const int N = in_sizes[3];
    const int E = in_sizes[4];
    const int G = in_sizes[6];

    int TE = (int)(((size_t)E + WROWS - 1) / WROWS);
    int TN = (int)(((size_t)N + WROWS - 1) / WROWS);
    int TG = (int)(((size_t)G + WROWS - 1) / WROWS);
    int TT = TE + TN + TG;

    float* R    = (float*)d_ws;                    // G*12 floats = 384 KB
    int* nstart = (int*)(R + 12 * (size_t)G);      // G+1 ints
    int* estart = nstart + (G + 1);                // G+1 ints
    int* tileg  = estart + (G + 1);                // TE+TN ints
    float* x_out = (float*)d_out;
    float* e_out = x_out + 3 * (size_t)N;
    float* y_out = e_out + 3 * (size_t)E;

    int prepThreads = G + 2 * (G + 1) + TE + TN;
    prep_kernel<<<(prepThreads + 255) / 256, 256, 0, stream>>>(
        axis, angle, apply_rand, node_batch, N, edge_batch, E, G,
        R, nstart, estart, tileg, TE, TN);

    apply_fused_pipe<<<(TT + TPW - 1) / TPW, 64, 0, stream>>>(
        edge_attr, e_out, E, TE,
        x, x_out, N, TN,
        y, y_out, G, TT,
        estart, nstart, tileg, R);
}

// Round 18
// 89.447 us; speedup vs baseline: 1.2030x; 1.2030x over previous
//
#include <hip/hip_runtime.h>
#include <math.h>

#define TWO_PI_F 6.283185307179586f
#define WROWS 256          // rows per wave-tile (3 KB LDS)
#define WBLK  64           // one wave per block

typedef float f32x4 __attribute__((ext_vector_type(4)));

__device__ __forceinline__ int lower_bound_dev(const int* __restrict__ b,
                                               int n, int g) {
    int lo = 0, hi = n;
    while (lo < hi) {
        int mid = (lo + hi) >> 1;
        if (b[mid] < g) lo = mid + 1; else hi = mid;
    }
    return lo;
}

// ONE prep kernel, role-split by global thread id:
//   [0, G)            : rotation matrix R[g] (12 floats, rows at f4 0,1,2)
//   [G, +(G+1))       : nstart[g] = lower_bound(node_batch, g)
//   [.., +(G+1))      : estart[g] = lower_bound(edge_batch, g)
//   [.., +TE+TN)      : tileg[t]: t<TE -> edge_batch[t*WROWS], else node
__global__ void prep_kernel(const float* __restrict__ axis,
                            const float* __restrict__ angle,
                            const float* __restrict__ apply_rand,
                            const int* __restrict__ nb, int N,
                            const int* __restrict__ eb, int E, int G,
                            float* __restrict__ R,
                            int* __restrict__ nstart, int* __restrict__ estart,
                            int* __restrict__ tileg, int TE, int TN) {
    int i = blockIdx.x * blockDim.x + threadIdx.x;
    if (i < G) {
        int g = i;
        float a = axis[3 * g + 0];
        float b = axis[3 * g + 1];
        float c = axis[3 * g + 2];
        float inv = rsqrtf(a * a + b * b + c * c);
        a *= inv; b *= inv; c *= inv;
        float th = angle[g] * TWO_PI_F;
        float s, co;
        sincosf(th, &s, &co);
        float omc = 1.0f - co;

        float r00 = 1.0f - omc * (b * b + c * c);
        float r01 = -s * c + omc * (a * b);
        float r02 =  s * b + omc * (a * c);
        float r10 =  s * c + omc * (a * b);
        float r11 = 1.0f - omc * (a * a + c * c);
        float r12 = -s * a + omc * (b * c);
        float r20 = -s * b + omc * (a * c);
        float r21 =  s * a + omc * (b * c);
        float r22 = 1.0f - omc * (a * a + b * b);

        if (!(apply_rand[g] < 0.5f)) {
            r00 = 1.0f; r01 = 0.0f; r02 = 0.0f;
            r10 = 0.0f; r11 = 1.0f; r12 = 0.0f;
            r20 = 0.0f; r21 = 0.0f; r22 = 1.0f;
        }
        float4* Rg = reinterpret_cast<float4*>(R + 12 * (size_t)g);
        Rg[0] = make_float4(r00, r01, r02, 0.0f);
        Rg[1] = make_float4(r10, r11, r12, 0.0f);
        Rg[2] = make_float4(r20, r21, r22, 0.0f);
        return;
    }
    i -= G;
    if (i < G + 1) { nstart[i] = lower_bound_dev(nb, N, i); return; }
    i -= (G + 1);
    if (i < G + 1) { estart[i] = lower_bound_dev(eb, E, i); return; }
    i -= (G + 1);
    if (i < TE) {
        size_t rb = (size_t)i * WROWS;
        if (rb > (size_t)(E - 1)) rb = (size_t)(E - 1);
        tileg[i] = eb[rb];
        return;
    }
    i -= TE;
    if (i < TN) {
        int rb = i * WROWS;
        if (rb > N - 1) rb = N - 1;
        tileg[TE + i] = nb[rb];
        return;
    }
}

// Fused apply (wave-tile, 256 rows, ONE WAVE per block): unified tile list
// [0,TE) edge, [TE,TE+TN) node, [TE+TN, +TG) y — node/y tiles fill the edge
// work's dispatch tail instead of running as separate serialized launches.
// tileg broadcast + <=3-step walk (rows clamped to n-1, R12 lesson), LDS
// AoS shuffle, NT stores. Best measured configuration (R15: 90.3 us).
__global__ __launch_bounds__(WBLK) void apply_fused_wave(
        const float* __restrict__ ev, float* __restrict__ eo, int E, int TE,
        const float* __restrict__ xv, float* __restrict__ xo, int N, int TN,
        const float* __restrict__ yv, float* __restrict__ yo, int G,
        const int* __restrict__ estart, const int* __restrict__ nstart,
        const int* __restrict__ tileg,
        const float* __restrict__ R) {
    __shared__ float buf[WROWS * 3];
    float4* buf4 = reinterpret_cast<float4*>(buf);

    const int lane = threadIdx.x;
    const int t = blockIdx.x;

    const float* v; float* o; const int* start; int n; size_t rowBase;
    bool hasB;
    if (t < TE) {
        v = ev; o = eo; start = estart; n = E; hasB = true;
        rowBase = (size_t)t * WROWS;
    } else if (t < TE + TN) {
        int u = t - TE;
        v = xv; o = xo; start = nstart; n = N; hasB = true;
        rowBase = (size_t)u * WROWS;
    } else {
        int u = t - TE - TN;
        v = yv; o = yo; start = nullptr; n = G; hasB = false;
        rowBase = (size_t)u * WROWS;
    }

    int rows = n - (int)rowBase;
    if (rows > WROWS) rows = WROWS;
    const int floatsHere = rows * 3;
    const int f4Here = floatsHere >> 2;       // 192 for a full tile
    const int tailFloats = floatsHere & 3;
    const int nRow4 = rows >> 2;              // 64 for a full tile

    // ---- issue the input loads first (longest latency) ----
    float4 a0 = make_float4(0, 0, 0, 0), a1 = a0, a2 = a0;
    float aT = 0.f;
    {
        const float4* src = reinterpret_cast<const float4*>(v + rowBase * 3);
        if (lane < f4Here)       a0 = src[lane];
        if (lane + 64 < f4Here)  a1 = src[lane + 64];
        if (lane + 128 < f4Here) a2 = src[lane + 128];
        if (tailFloats && lane < tailFloats)
            aT = v[rowBase * 3 + (((size_t)f4Here) << 2) + lane];
    }

    // ---- group indices (overlaps the loads above; no binary search) ----
    int gs[4];
    if (hasB) {
        int g = tileg[t];                     // broadcast scalar load
        const int rowMax = n - 1;
        int row0 = (int)rowBase + 4 * lane;
#pragma unroll
        for (int r = 0; r < 4; ++r) {
            int row = row0 + r;
            if (row > rowMax) row = rowMax;
            while (start[g + 1] <= row) ++g;  // <=~3 steps per tile
            gs[r] = g;
        }
    } else {
        int b = (int)rowBase + 4 * lane;
        gs[0] = b; gs[1] = b + 1; gs[2] = b + 2; gs[3] = b + 3;
    }

    // ---- stage into LDS (single wave: barrier is just a waitcnt) ----
    if (lane < f4Here)       buf4[lane]       = a0;
    if (lane + 64 < f4Here)  buf4[lane + 64]  = a1;
    if (lane + 128 < f4Here) buf4[lane + 128] = a2;
    if (tailFloats && lane < tailFloats) buf[(f4Here << 2) + lane] = aT;
    __syncthreads();

    // ---- rotate 4 rows per lane, in place ----
    if (lane < nRow4) {
        float4 p0 = buf4[3 * lane + 0];
        float4 p1 = buf4[3 * lane + 1];
        float4 p2 = buf4[3 * lane + 2];
        float rowsv[4][3] = {
            {p0.x, p0.y, p0.z},
            {p0.w, p1.x, p1.y},
            {p1.z, p1.w, p2.x},
            {p2.y, p2.z, p2.w}};
        float oo[12];
#pragma unroll
        for (int r = 0; r < 4; ++r) {
            const float4* Rg = reinterpret_cast<const float4*>(R + 12 * (size_t)gs[r]);
            float4 R0 = Rg[0];
            float4 R1 = Rg[1];
            float4 R2 = Rg[2];
            float v0 = rowsv[r][0], v1 = rowsv[r][1], v2 = rowsv[r][2];
            oo[3 * r + 0] = R0.x * v0 + R0.y * v1 + R0.z * v2;
            oo[3 * r + 1] = R1.x * v0 + R1.y * v1 + R1.z * v2;
            oo[3 * r + 2] = R2.x * v0 + R2.y * v1 + R2.z * v2;
        }
        buf4[3 * lane + 0] = make_float4(oo[0], oo[1], oo[2], oo[3]);
        buf4[3 * lane + 1] = make_float4(oo[4], oo[5], oo[6], oo[7]);
        buf4[3 * lane + 2] = make_float4(oo[8], oo[9], oo[10], oo[11]);
    }
    // (rows % 4 tail: E, N, G all divisible by 4 here.)
    __syncthreads();

    // ---- NT store out ----
    {
        const f32x4* b4 = reinterpret_cast<const f32x4*>(buf);
        f32x4* dst = reinterpret_cast<f32x4*>(o + rowBase * 3);
        if (lane < f4Here) {
            f32x4 val = b4[lane];
            __builtin_nontemporal_store(val, &dst[lane]);
        }
        if (lane + 64 < f4Here) {
            f32x4 val = b4[lane + 64];
            __builtin_nontemporal_store(val, &dst[lane + 64]);
        }
        if (lane + 128 < f4Here) {
            f32x4 val = b4[lane + 128];
            __builtin_nontemporal_store(val, &dst[lane + 128]);
        }
        if (tailFloats && lane < tailFloats) {
            int fi = (f4Here << 2) + lane;
            __builtin_nontemporal_store(buf[fi], &o[rowBase * 3 + fi]);
        }
    }
}

extern "C" void kernel_launch(void* const* d_in, const int* in_sizes, int n_in,
                              void* d_out, int out_size, void* d_ws, size_t ws_size,
                              hipStream_t stream) {
    const float* x          = (const float*)d_in[0];
    const float* edge_attr  = (const float*)d_in[1];
    const float* y          = (const float*)d_in[2];
    const int*   node_batch = (const int*)d_in[3];
    const int*   edge_batch = (const int*)d_in[4];
    const float* axis       = (const float*)d_in[5];
    const float* angle      = (const float*)d_in[6];
    const float* apply_rand = (const float*)d_in[7];

    const int N = in_sizes[3];
    const int E = in_sizes[4];
    const int G = in_sizes[6];

    int TE = (int)(((size_t)E + WROWS - 1) / WROWS);
    int TN = (int)(((size_t)N + WROWS - 1) / WROWS);
    int TG = (int)(((size_t)G + WROWS - 1) / WROWS);

    float* R    = (float*)d_ws;                    // G*12 floats = 384 KB
    int* nstart = (int*)(R + 12 * (size_t)G);      // G+1 ints
    int* estart = nstart + (G + 1);                // G+1 ints
    int* tileg  = estart + (G + 1);                // TE+TN ints
    float* x_out = (float*)d_out;
    float* e_out = x_out + 3 * (size_t)N;
    float* y_out = e_out + 3 * (size_t)E;

    int prepThreads = G + 2 * (G + 1) + TE + TN;
    prep_kernel<<<(prepThreads + 255) / 256, 256, 0, stream>>>(
        axis, angle, apply_rand, node_batch, N, edge_batch, E, G,
        R, nstart, estart, tileg, TE, TN);

    apply_fused_wave<<<TE + TN + TG, WBLK, 0, stream>>>(
        edge_attr, e_out, E, TE,
        x, x_out, N, TN,
        y, y_out, G,
        estart, nstart, tileg, R);
}